// Round 1
// baseline (125.543 us; speedup 1.0000x reference)
//
#include <hip/hip_runtime.h>

// NCC loss, fully fused single pass.
// Volume [B=2][1][D=160][H=192][W=160] fp32. Window 9^3, zero-padded, /729.
// Structure per block: tile TH=16 x TW=32 in (H,W), stream a ZC=40 z-chunk.
//   A: global->LDS products (I, J, I2, J2, IJ) for (TH+8)x(TW+8) halo tile (float4)
//   B: W-axis 9-tap sliding sums (float4 reads/writes)  prod -> hsum
//   C: H-axis 9-tap sliding sums (float4, 4-col strips)  hsum -> vsum
//   D: per-pixel 9-deep register ring along D + cc epilogue + fp32 partial
// Final: wave shfl reduce -> double atomicAdd -> tiny finalize kernel.

#define NB 2
#define ND 160
#define NH 192
#define NW 160
#define TH 16
#define TW 32
#define ZC 40
#define HR (TH + 8)   // 24 halo rows
#define HC (TW + 8)   // 40 halo cols
#define PSTR 44       // prod row stride (>=40, mult of 4 for b128)
#define HSTR 36       // hsum row stride (>=32, mult of 4)
#define VSTR 36       // vsum row stride
#define NTH 512
#define NSTEP (ZC + 8)   // 48 planes touched per chunk
#define NITER 54         // padded to multiple of 9 for static ring slots

__device__ __forceinline__ float4 f4add(float4 a, float4 b) {
    return make_float4(a.x + b.x, a.y + b.y, a.z + b.z, a.w + b.w);
}
__device__ __forceinline__ float4 f4sub(float4 a, float4 b) {
    return make_float4(a.x - b.x, a.y - b.y, a.z - b.z, a.w - b.w);
}

__global__ __launch_bounds__(NTH, 4) void ncc_main(
        const float* __restrict__ I, const float* __restrict__ J,
        double* __restrict__ gacc) {
    __shared__ float prod[5][HR][PSTR];  // 21.1 KB
    __shared__ float hsum[5][HR][HSTR];  // 17.3 KB
    __shared__ float vsum[5][TH][VSTR];  // 11.5 KB

    const int tid = threadIdx.x;
    const int tx = tid & 31;
    const int ty = tid >> 5;

    const int tilesW = NW / TW;                 // 5
    const int tileW = blockIdx.x % tilesW;
    const int tileH = blockIdx.x / tilesW;      // 0..11
    const int w0 = tileW * TW;
    const int h0 = tileH * TH;
    const int z0 = blockIdx.y * ZC;
    const int b  = blockIdx.z;
    const size_t volBase = (size_t)b * ND * NH * NW;

    // ---- A-task decode (tid < 240): 24 rows x 10 float4 slots ----
    const int a_r = tid / 10;
    const int a_c = (tid - a_r * 10) * 4;
    const bool a_on = (tid < 240);
    const int a_h = h0 - 4 + a_r;
    const int a_w = w0 - 4 + a_c;
    // W boundaries (0 and 160) are multiples of 4, so each float4 is fully in or out.
    const bool a_hw = a_on && (a_h >= 0) && (a_h < NH) && (a_w >= 0) && (a_w < NW);

    // ---- B-task decode (tid < 240): (field, row, half-row of 16 outputs) ----
    const int b_f = tid / 48;
    const int b_rem = tid - b_f * 48;
    const int b_r = b_rem >> 1;
    const int b_c0 = (b_rem & 1) << 4;

    // ---- C-task decode (tid < 160): (field, 4-col group, 4-row strip) ----
    const int c_f = tid >> 5;
    const int c_cg = (tid & 31) >> 2;
    const int c_r0 = (tid & 3) << 2;
    const int c_c0 = c_cg << 2;

    float ring[5][9];
    float acc[5];
#pragma unroll
    for (int f = 0; f < 5; ++f) {
        acc[f] = 0.f;
#pragma unroll
        for (int k = 0; k < 9; ++k) ring[f][k] = 0.f;
    }
    float partial = 0.f;

#pragma unroll 1
    for (int ii = 0; ii < NITER; ii += 9) {
#pragma unroll
        for (int jj = 0; jj < 9; ++jj) {       // jj == i % 9 : static ring slot
            const int i = ii + jj;
            const int zt = z0 - 4 + i;
            const bool zok = (zt >= 0) && (zt < ND) && (i < NSTEP);
            if (zok) {
                // ---------- A: load raw, write 5 product planes ----------
                if (a_on) {
                    float4 vI = make_float4(0.f, 0.f, 0.f, 0.f);
                    float4 vJ = vI;
                    if (a_hw) {
                        const size_t idx = volBase + ((size_t)zt * NH + a_h) * NW + a_w;
                        vI = *(const float4*)(I + idx);
                        vJ = *(const float4*)(J + idx);
                    }
                    *(float4*)&prod[0][a_r][a_c] = vI;
                    *(float4*)&prod[1][a_r][a_c] = vJ;
                    *(float4*)&prod[2][a_r][a_c] =
                        make_float4(vI.x * vI.x, vI.y * vI.y, vI.z * vI.z, vI.w * vI.w);
                    *(float4*)&prod[3][a_r][a_c] =
                        make_float4(vJ.x * vJ.x, vJ.y * vJ.y, vJ.z * vJ.z, vJ.w * vJ.w);
                    *(float4*)&prod[4][a_r][a_c] =
                        make_float4(vI.x * vJ.x, vI.y * vJ.y, vI.z * vJ.z, vI.w * vJ.w);
                }
                __syncthreads();
                // ---------- B: W-axis 9-tap sliding sums ----------
                if (a_on) {
                    float p[24];
#pragma unroll
                    for (int k = 0; k < 6; ++k)
                        *(float4*)&p[k * 4] = *(const float4*)&prod[b_f][b_r][b_c0 + k * 4];
                    float s = p[0];
#pragma unroll
                    for (int k = 1; k < 9; ++k) s += p[k];
#pragma unroll
                    for (int g = 0; g < 4; ++g) {
                        float4 ov;
                        ov.x = s;
                        s += p[g * 4 + 9]  - p[g * 4 + 0]; ov.y = s;
                        s += p[g * 4 + 10] - p[g * 4 + 1]; ov.z = s;
                        s += p[g * 4 + 11] - p[g * 4 + 2]; ov.w = s;
                        *(float4*)&hsum[b_f][b_r][b_c0 + g * 4] = ov;
                        if (g < 3) s += p[g * 4 + 12] - p[g * 4 + 3];
                    }
                }
                __syncthreads();
                // ---------- C: H-axis 9-tap sliding sums (4 cols x 4 rows) ----------
                if (tid < 160) {
                    float4 r0v = *(const float4*)&hsum[c_f][c_r0 + 0][c_c0];
                    float4 r1v = *(const float4*)&hsum[c_f][c_r0 + 1][c_c0];
                    float4 r2v = *(const float4*)&hsum[c_f][c_r0 + 2][c_c0];
                    float4 s4 = f4add(f4add(r0v, r1v), r2v);
#pragma unroll
                    for (int k = 3; k < 9; ++k)
                        s4 = f4add(s4, *(const float4*)&hsum[c_f][c_r0 + k][c_c0]);
                    *(float4*)&vsum[c_f][c_r0 + 0][c_c0] = s4;
                    s4 = f4sub(f4add(s4, *(const float4*)&hsum[c_f][c_r0 + 9][c_c0]), r0v);
                    *(float4*)&vsum[c_f][c_r0 + 1][c_c0] = s4;
                    s4 = f4sub(f4add(s4, *(const float4*)&hsum[c_f][c_r0 + 10][c_c0]), r1v);
                    *(float4*)&vsum[c_f][c_r0 + 2][c_c0] = s4;
                    s4 = f4sub(f4add(s4, *(const float4*)&hsum[c_f][c_r0 + 11][c_c0]), r2v);
                    *(float4*)&vsum[c_f][c_r0 + 3][c_c0] = s4;
                }
                __syncthreads();
            }
            // ---------- D: per-pixel ring along D, cc epilogue ----------
            {
#pragma unroll
                for (int f = 0; f < 5; ++f) {
                    const float v = zok ? vsum[f][ty][tx] : 0.f;
                    acc[f] += v - ring[f][jj];
                    ring[f][jj] = v;
                }
                if (i >= 8 && i < NSTEP) {
                    const float Is = acc[0], Js = acc[1];
                    const float I2 = acc[2], J2 = acc[3], IJ = acc[4];
                    const float inv = 1.0f / 729.0f;
                    const float uI = Is * inv, uJ = Js * inv;
                    const float cross = IJ - uJ * Is - uI * Js + uI * uJ * 729.0f;
                    const float Iv = I2 - 2.0f * uI * Is + uI * uI * 729.0f;
                    const float Jv = J2 - 2.0f * uJ * Js + uJ * uJ * 729.0f;
                    partial += cross * cross / (Iv * Jv + 1e-5f);
                }
            }
            __syncthreads();
        }
    }

    // ---------- reduction: wave shfl -> double atomic ----------
    double dp = (double)partial;
#pragma unroll
    for (int off = 32; off > 0; off >>= 1)
        dp += __shfl_down(dp, off, 64);
    if ((tid & 63) == 0) atomicAdd(gacc, dp);
}

__global__ void ncc_fin(const double* __restrict__ gacc, float* __restrict__ out) {
    out[0] = (float)(-gacc[0] / (double)((long long)NB * ND * NH * NW));
}

extern "C" void kernel_launch(void* const* d_in, const int* in_sizes, int n_in,
                              void* d_out, int out_size, void* d_ws, size_t ws_size,
                              hipStream_t stream) {
    const float* I = (const float*)d_in[0];   // y_true
    const float* J = (const float*)d_in[1];   // y_pred
    double* ws = (double*)d_ws;

    hipMemsetAsync(d_ws, 0, sizeof(double), stream);   // graph-capture safe

    dim3 grid((NW / TW) * (NH / TH), ND / ZC, NB);     // 60 x 4 x 2 = 480 blocks
    ncc_main<<<grid, NTH, 0, stream>>>(I, J, ws);
    ncc_fin<<<1, 1, 0, stream>>>(ws, (float*)d_out);
}